// Round 5
// baseline (1647.806 us; speedup 1.0000x reference)
//
#include <hip/hip_runtime.h>
#include <hip/hip_bf16.h>
#include <math.h>

#define N_PTS 65534
#define GH 180
#define GW 360
#define NCELL (GH*GW)
#define PI_F 3.14159265358979323846f

typedef __bf16 bf16;
typedef bf16 bf16x8 __attribute__((ext_vector_type(8)));
typedef float f32x4 __attribute__((ext_vector_type(4)));

// wave-level LDS fence: drains LDS queue + compiler memory barrier.
// Prevents the scheduler from reordering wave-private LDS write->read / read->write
// pairs that have no data dependency (R3/R4 corruption root cause).
#define LDS_FENCE() asm volatile("s_waitcnt lgkmcnt(0)" ::: "memory")

static __device__ __forceinline__ f32x4 mfma16(bf16x8 a, bf16x8 b, f32x4 c){
    return __builtin_amdgcn_mfma_f32_16x16x32_bf16(a,b,c,0,0,0);
}

// ---------------- generic transpose: src K x N (row major) -> dst N x KP bf16, zero-pad k>=K
__global__ void tr_kernel(const float* __restrict__ src, bf16* __restrict__ dst,
                          int K, int N, int KP){
    int idx = blockIdx.x*256 + threadIdx.x;
    if (idx >= N*KP) return;
    int n = idx / KP, k = idx - n*KP;
    float v = (k < K) ? src[(size_t)k*N + n] : 0.f;
    dst[idx] = (bf16)v;
}

// Wqkv (2,128,384) -> WqT [lay][hd][s][d=16][k=128]
__global__ void tr_qkv_kernel(const float* __restrict__ src, bf16* __restrict__ dst){
    int idx = blockIdx.x*256 + threadIdx.x;
    if (idx >= 2*49152) return;
    int lay = idx / 49152, r = idx % 49152;
    int hd = r / 6144,  r2 = r % 6144;
    int s3 = r2 / 2048, r3 = r2 % 2048;
    int d  = r3 / 128,  k  = r3 % 128;
    dst[idx] = (bf16)src[(size_t)lay*49152 + (size_t)k*384 + s3*128 + hd*16 + d];
}

// Wf2 (2,512,128) -> Wf2C [lay][ch=8][n=128][kk=64]
__global__ void tr_f2_kernel(const float* __restrict__ src, bf16* __restrict__ dst){
    int idx = blockIdx.x*256 + threadIdx.x;
    if (idx >= 2*65536) return;
    int lay = idx / 65536, r = idx % 65536;
    int ch = r / 8192, r2 = r % 8192;
    int n  = r2 / 64,  kk = r2 % 64;
    dst[idx] = (bf16)src[(size_t)lay*65536 + (size_t)(ch*64+kk)*128 + n];
}

// ---------------- per-point grid index + counts
__global__ void count_kernel(const float* __restrict__ x, int* __restrict__ flat,
                             int* __restrict__ cnt){
    int p = blockIdx.x*256 + threadIdx.x;
    if (p >= N_PTS) return;
    float lat = x[p*24+0], lon = x[p*24+1];
    if (lat == -90.0f) lat += 1e-4f;
    int lati = (int)floorf(90.0f - lat);
    int loni = (180 + (int)floorf(lon + 180.0f)) % 360;
    lati = min(max(lati,0),GH-1);
    loni = min(max(loni,0),GW-1);
    int f = lati*GW + loni;
    flat[p] = f;
    atomicAdd(&cnt[f], 1);
}

// ================= fully fused: features -> embed -> 2 layers -> comb -> scatter
// wave = 8 points = 32 tokens (2 M-tiles). block = 4 independent waves.
// h stays in registers; all B-fragments stream directly from L2 (weights ~1.4MB, L2-resident);
// all LDS is wave-private; wave-level LDS_FENCEs replace block barriers.
__global__ __launch_bounds__(256,3) void fused_kernel(
    const float* __restrict__ x,
    const bf16* __restrict__ WembT, const float* __restrict__ b_emb,
    const bf16* __restrict__ WqT,   const float* __restrict__ bqkv,
    const bf16* __restrict__ WoT,   const float* __restrict__ bo,
    const bf16* __restrict__ Wf1T,  const float* __restrict__ bf1,
    const bf16* __restrict__ Wf2C,  const float* __restrict__ bf2,
    const bf16* __restrict__ WcT,   const float* __restrict__ b_comb,
    const float* __restrict__ ln1s, const float* __restrict__ ln1b,
    const float* __restrict__ ln2s, const float* __restrict__ ln2b,
    const int* __restrict__ flat,   const int* __restrict__ cnt,
    float* __restrict__ out)
{
    __shared__ __align__(16) bf16  tile[4][32][136];  // per-wave transpose tile (34,816 B)
    __shared__ __align__(16) float tfb[4][512];       // per-wave f32 embed bounce (8,192 B)
    const int wv = threadIdx.x>>6, l = threadIdx.x&63;
    const int g = l>>4, c = l&15;
    const int pb = blockIdx.x*32 + wv*8;

    // ---- features into tile rows 0..7 (points), rows 8..15 zeroed (M-tile pad)
    {
        const int pl = l>>3, w = l&7;
        const int p = pb + pl;
        const bool valid = (p < N_PTS);
        float lat=0.f, lon=0.f, t=0.f;
        if (valid){ lat=x[p*24+0]; lon=x[p*24+1]; t=x[p*24+2]; }
        if (lat == -90.0f) lat += 1e-4f;
        float pvs[3] = { -lat - floorf(-lat), lon - floorf(lon), t + 1.0f };
        #pragma unroll
        for (int i=0;i<12;++i){
            int f = w*12 + i;
            float val;
            if (f >= 75) val = 0.f;
            else if (f < 24){
                if (f==0)      val = lat*(1.f/90.f);
                else if (f==1) val = lon*(1.f/180.f);
                else if (f==2) val = t*(1.f/12.f);
                else           val = valid ? x[p*24+f] : 0.f;
            } else if (f<27) val = pvs[f-24];
            else if (f<51){ int q=f-27; val = sinf(pvs[q>>3]*(float)(1<<(q&7))*PI_F); }
            else          { int q=f-51; val = cosf(pvs[q>>3]*(float)(1<<(q&7))*PI_F); }
            if (!valid) val = 0.f;
            tile[wv][pl][f]   = (bf16)val;
            tile[wv][8+pl][f] = (bf16)0.f;
        }
    }
    LDS_FENCE();                     // feature writes -> afe reads
    // embed A-frags (rows = points 0..15, K=96)
    bf16x8 afe[3];
    #pragma unroll
    for (int ks=0;ks<3;++ks) afe[ks] = *(const bf16x8*)&tile[wv][c][ks*32+g*8];

    f32x4 h[2][8];
    float* tf = &tfb[wv][0];   // 8x64 f32 bounce, separate typed buffer
    // ---- embed: 8 chunks of 64 output cols, B direct from L2
    for (int ch=0; ch<8; ++ch){
        const int tk = ch>>1;
        #pragma unroll
        for (int nt=0; nt<4; ++nt){
            f32x4 acc = {0.f,0.f,0.f,0.f};
            const bf16* bp = WembT + (size_t)(ch*64+nt*16+c)*96 + g*8;
            #pragma unroll
            for (int ks=0;ks<3;++ks)
                acc = mfma16(afe[ks], *(const bf16x8*)(bp+ks*32), acc);
            float bb = b_emb[ch*64 + nt*16 + c];
            if (g<2){
                #pragma unroll
                for (int j=0;j<4;++j) tf[(g*4+j)*64 + nt*16 + c] = acc[j] + bb;
            }
        }
        LDS_FENCE();                 // tf writes -> tf reads (cross-lane)
        #pragma unroll
        for (int mt=0;mt<2;++mt)
            #pragma unroll
            for (int nt=0;nt<4;++nt)
                h[mt][(ch&1)*4+nt][tk] = tf[(mt*4+g)*64 + nt*16 + c];
        LDS_FENCE();                 // tf reads -> next chunk's tf writes (WAR)
    }

    // ---- transformer layers
    for (int lay=0; lay<2; ++lay){
        float ls[8], lb[8];
        // ===== LN1 -> tile (bf16)
        #pragma unroll
        for (int n=0;n<8;++n){ ls[n]=ln1s[lay*128+n*16+c]; lb[n]=ln1b[lay*128+n*16+c]; }
        #pragma unroll
        for (int mt=0;mt<2;++mt)
            #pragma unroll
            for (int j=0;j<4;++j){
                float s=0.f,q=0.f;
                #pragma unroll
                for (int n=0;n<8;++n){ float v=h[mt][n][j]; s+=v; q+=v*v; }
                s += __shfl_xor(s,1); s += __shfl_xor(s,2); s += __shfl_xor(s,4); s += __shfl_xor(s,8);
                q += __shfl_xor(q,1); q += __shfl_xor(q,2); q += __shfl_xor(q,4); q += __shfl_xor(q,8);
                float m = s*(1.f/128.f);
                float var = q*(1.f/128.f) - m*m;
                float rs = rsqrtf(var + 1e-5f);
                #pragma unroll
                for (int n=0;n<8;++n)
                    tile[wv][mt*16+g*4+j][n*16+c] = (bf16)((h[mt][n][j]-m)*rs*ls[n]+lb[n]);
            }
        LDS_FENCE();                 // LN1 writes -> af reads
        bf16x8 af[2][4];
        #pragma unroll
        for (int mt=0;mt<2;++mt)
            #pragma unroll
            for (int ks=0;ks<4;++ks)
                af[mt][ks] = *(const bf16x8*)&tile[wv][mt*16+c][ks*32+g*8];
        LDS_FENCE();                 // af reads -> ot writes (WAR)
        // ===== QKV + in-register attention, per head (ot overwrites tile)
        for (int hd=0; hd<8; ++hd){
            const bf16* wq = WqT + (size_t)(lay*8+hd)*6144;
            f32x4 acc[3][2];
            #pragma unroll
            for (int s3=0;s3<3;++s3){
                bf16x8 bq[4];
                const bf16* bp = wq + (s3*16+c)*128 + g*8;
                #pragma unroll
                for (int ks=0;ks<4;++ks) bq[ks] = *(const bf16x8*)(bp+ks*32);
                float bias = bqkv[lay*384 + s3*128 + hd*16 + c];
                #pragma unroll
                for (int mt=0;mt<2;++mt){
                    f32x4 a = {0.f,0.f,0.f,0.f};
                    #pragma unroll
                    for (int ks=0;ks<4;++ks)
                        a = mfma16(af[mt][ks], bq[ks], a);
                    #pragma unroll
                    for (int j=0;j<4;++j) a[j] += bias;
                    acc[s3][mt] = a;
                }
            }
            #pragma unroll
            for (int mt=0;mt<2;++mt){
                #pragma unroll
                for (int j=0;j<4;++j) acc[0][mt][j] *= 0.25f;
                float att[16];
                #pragma unroll
                for (int i=0;i<4;++i)
                    #pragma unroll
                    for (int j=0;j<4;++j){
                        float t = acc[0][mt][i]*acc[1][mt][j];
                        t += __shfl_xor(t,1); t += __shfl_xor(t,2);
                        t += __shfl_xor(t,4); t += __shfl_xor(t,8);
                        att[i*4+j]=t;
                    }
                #pragma unroll
                for (int i=0;i<4;++i){
                    float m = fmaxf(fmaxf(att[i*4],att[i*4+1]),fmaxf(att[i*4+2],att[i*4+3]));
                    float e0=__expf(att[i*4]-m),   e1=__expf(att[i*4+1]-m);
                    float e2=__expf(att[i*4+2]-m), e3=__expf(att[i*4+3]-m);
                    float inv = 1.f/(e0+e1+e2+e3);
                    float o = (e0*acc[2][mt][0]+e1*acc[2][mt][1]+e2*acc[2][mt][2]+e3*acc[2][mt][3])*inv;
                    tile[wv][mt*16+g*4+i][hd*16+c] = (bf16)o;
                }
            }
        }
        LDS_FENCE();                 // ot writes -> oa reads
        // ===== O-proj, residual accumulates in h
        bf16x8 oa[2][4];
        #pragma unroll
        for (int mt=0;mt<2;++mt)
            #pragma unroll
            for (int ks=0;ks<4;++ks)
                oa[mt][ks] = *(const bf16x8*)&tile[wv][mt*16+c][ks*32+g*8];
        LDS_FENCE();                 // oa reads -> LN2 writes (WAR)
        #pragma unroll
        for (int nh=0;nh<8;++nh){
            bf16x8 bo_[4];
            const bf16* bp = WoT + (size_t)lay*16384 + (nh*16+c)*128 + g*8;
            #pragma unroll
            for (int ks=0;ks<4;++ks) bo_[ks] = *(const bf16x8*)(bp+ks*32);
            float bias = bo[lay*128 + nh*16 + c];
            #pragma unroll
            for (int mt=0;mt<2;++mt){
                f32x4 a = h[mt][nh];
                #pragma unroll
                for (int ks=0;ks<4;++ks)
                    a = mfma16(oa[mt][ks], bo_[ks], a);
                #pragma unroll
                for (int j=0;j<4;++j) a[j]+=bias;
                h[mt][nh]=a;
            }
        }
        // ===== LN2 -> tile
        #pragma unroll
        for (int n=0;n<8;++n){ ls[n]=ln2s[lay*128+n*16+c]; lb[n]=ln2b[lay*128+n*16+c]; }
        #pragma unroll
        for (int mt=0;mt<2;++mt)
            #pragma unroll
            for (int j=0;j<4;++j){
                float s=0.f,q=0.f;
                #pragma unroll
                for (int n=0;n<8;++n){ float v=h[mt][n][j]; s+=v; q+=v*v; }
                s += __shfl_xor(s,1); s += __shfl_xor(s,2); s += __shfl_xor(s,4); s += __shfl_xor(s,8);
                q += __shfl_xor(q,1); q += __shfl_xor(q,2); q += __shfl_xor(q,4); q += __shfl_xor(q,8);
                float m = s*(1.f/128.f);
                float var = q*(1.f/128.f) - m*m;
                float rs = rsqrtf(var + 1e-5f);
                #pragma unroll
                for (int n=0;n<8;++n)
                    tile[wv][mt*16+g*4+j][n*16+c] = (bf16)((h[mt][n][j]-m)*rs*ls[n]+lb[n]);
            }
        LDS_FENCE();                 // LN2 writes -> f1a reads
        bf16x8 f1a[2][4];
        #pragma unroll
        for (int mt=0;mt<2;++mt)
            #pragma unroll
            for (int ks=0;ks<4;++ks)
                f1a[mt][ks] = *(const bf16x8*)&tile[wv][mt*16+c][ks*32+g*8];
        LDS_FENCE();                 // f1a reads -> gt writes (WAR)
        // ===== FFN: 8 chunks of 64 hidden cols; FFN2 accumulates into h (residual)
        for (int ch=0; ch<8; ++ch){
            #pragma unroll
            for (int nt=0;nt<4;++nt){
                bf16x8 b1[4];
                const bf16* bp = Wf1T + (size_t)lay*65536 + (ch*64+nt*16+c)*128 + g*8;
                #pragma unroll
                for (int ks=0;ks<4;++ks) b1[ks] = *(const bf16x8*)(bp+ks*32);
                float bias = bf1[lay*512 + ch*64 + nt*16 + c];
                #pragma unroll
                for (int mt=0;mt<2;++mt){
                    f32x4 a = {0.f,0.f,0.f,0.f};
                    #pragma unroll
                    for (int ks=0;ks<4;++ks)
                        a = mfma16(f1a[mt][ks], b1[ks], a);
                    #pragma unroll
                    for (int j=0;j<4;++j){
                        float xx = a[j]+bias;
                        float zz = 0.7978845608028654f*(xx+0.044715f*xx*xx*xx);
                        float u  = __expf(2.f*zz);
                        float th = (u-1.f)/(u+1.f);
                        tile[wv][mt*16+g*4+j][nt*16+c] = (bf16)(0.5f*xx*(1.f+th));
                    }
                }
            }
            LDS_FENCE();             // gt writes -> ga reads (RAW; was STAGE barrier in R2)
            bf16x8 ga[2][2];
            #pragma unroll
            for (int mt=0;mt<2;++mt)
                #pragma unroll
                for (int ks=0;ks<2;++ks)
                    ga[mt][ks] = *(const bf16x8*)&tile[wv][mt*16+c][ks*32+g*8];
            LDS_FENCE();             // ga reads -> next chunk's gt writes (WAR)
            #pragma unroll
            for (int nt2=0;nt2<8;++nt2){
                bf16x8 b2[2];
                const bf16* bp = Wf2C + (size_t)(lay*8+ch)*8192 + (nt2*16+c)*64 + g*8;
                #pragma unroll
                for (int ks=0;ks<2;++ks) b2[ks] = *(const bf16x8*)(bp+ks*32);
                #pragma unroll
                for (int mt=0;mt<2;++mt){
                    f32x4 a = h[mt][nt2];
                    #pragma unroll
                    for (int ks=0;ks<2;++ks)
                        a = mfma16(ga[mt][ks], b2[ks], a);
                    h[mt][nt2]=a;
                }
            }
        }
        #pragma unroll
        for (int nt2=0;nt2<8;++nt2){
            float bias = bf2[lay*128 + nt2*16+c];
            #pragma unroll
            for (int mt=0;mt<2;++mt)
                #pragma unroll
                for (int j=0;j<4;++j) h[mt][nt2][j]+=bias;
        }
    }

    // ---- comb + scatter-mean. tk-split GEMMs reuse the token-major tile.
    #pragma unroll
    for (int mt=0;mt<2;++mt)
        #pragma unroll
        for (int n=0;n<8;++n)
            #pragma unroll
            for (int j=0;j<4;++j)
                tile[wv][mt*16+g*4+j][n*16+c] = (bf16)h[mt][n][j];
    LDS_FENCE();                     // h writes -> afc reads
    bf16x8 afc[4][4];
    #pragma unroll
    for (int tk=0;tk<4;++tk)
        #pragma unroll
        for (int ks=0;ks<4;++ks)
            afc[tk][ks] = *(const bf16x8*)&tile[wv][(c&7)*4+tk][ks*32+g*8];
    int flj[4]; float ivj[4];
    #pragma unroll
    for (int j=0;j<4;++j){
        int p = pb + g*4 + j;
        if (g<2 && p<N_PTS){ int f=flat[p]; flj[j]=f; ivj[j]=1.f/fmaxf((float)cnt[f],1.f); }
        else { flj[j]=0; ivj[j]=0.f; }
    }
    for (int chk=0; chk<32; ++chk){
        f32x4 a = {0.f,0.f,0.f,0.f};
        const bf16* bp = WcT + (size_t)(chk*16+c)*512 + g*8;
        #pragma unroll
        for (int tk=0;tk<4;++tk)
            #pragma unroll
            for (int ks=0;ks<4;++ks)
                a = mfma16(afc[tk][ks], *(const bf16x8*)(bp + tk*128 + ks*32), a);
        if (g<2){
            float bb = b_comb[chk*16+c];
            #pragma unroll
            for (int j=0;j<4;++j){
                int p = pb + g*4 + j;
                if (p < N_PTS)
                    atomicAdd(&out[(size_t)flj[j]*512 + chk*16 + c], (a[j]+bb)*ivj[j]);
            }
        }
    }
}

extern "C" void kernel_launch(void* const* d_in, const int* in_sizes, int n_in,
                              void* d_out, int out_size, void* d_ws, size_t ws_size,
                              hipStream_t stream){
    (void)in_sizes; (void)n_in; (void)ws_size;
    const float* x      = (const float*)d_in[0];
    const float* W_emb  = (const float*)d_in[1];
    const float* b_emb  = (const float*)d_in[2];
    const float* ln1_s  = (const float*)d_in[3];
    const float* ln1_b  = (const float*)d_in[4];
    const float* Wqkv   = (const float*)d_in[5];
    const float* bqkv   = (const float*)d_in[6];
    const float* Wo     = (const float*)d_in[7];
    const float* bo     = (const float*)d_in[8];
    const float* ln2_s  = (const float*)d_in[9];
    const float* ln2_b  = (const float*)d_in[10];
    const float* Wf1    = (const float*)d_in[11];
    const float* bf1    = (const float*)d_in[12];
    const float* Wf2    = (const float*)d_in[13];
    const float* bf2    = (const float*)d_in[14];
    const float* W_comb = (const float*)d_in[15];
    const float* b_comb = (const float*)d_in[16];
    float* out = (float*)d_out;

    char* ws = (char*)d_ws;
    size_t off = 0;
    auto alloc = [&](size_t bytes)->char*{
        char* p = ws + off; off = (off + bytes + 255) & ~(size_t)255; return p;
    };
    bf16* WembT = (bf16*) alloc((size_t)512*96*2);
    bf16* WqT   = (bf16*) alloc((size_t)2*49152*2);
    bf16* WoT   = (bf16*) alloc((size_t)2*16384*2);
    bf16* Wf1T  = (bf16*) alloc((size_t)2*65536*2);
    bf16* Wf2C  = (bf16*) alloc((size_t)2*65536*2);
    bf16* WcT   = (bf16*) alloc((size_t)512*512*2);
    int*  flat  = (int*)  alloc((size_t)N_PTS*4);
    int*  cnt   = (int*)  alloc((size_t)NCELL*4);

    hipMemsetAsync(d_out, 0, (size_t)out_size*sizeof(float), stream);
    hipMemsetAsync(cnt, 0, (size_t)NCELL*4, stream);

    auto tr = [&](const float* s, bf16* d, int K, int N, int KP){
        int tot = N*KP;
        tr_kernel<<<(tot+255)/256, 256, 0, stream>>>(s, d, K, N, KP);
    };
    tr(W_emb, WembT, 75, 512, 96);
    tr_qkv_kernel<<<(2*49152+255)/256, 256, 0, stream>>>(Wqkv, WqT);
    for (int lay=0; lay<2; ++lay){
        tr(Wo  + (size_t)lay*16384, WoT  + (size_t)lay*16384, 128, 128, 128);
        tr(Wf1 + (size_t)lay*65536, Wf1T + (size_t)lay*65536, 128, 512, 128);
    }
    tr_f2_kernel<<<(2*65536+255)/256, 256, 0, stream>>>(Wf2, Wf2C);
    tr(W_comb, WcT, 512, 512, 512);

    count_kernel<<<(N_PTS+255)/256, 256, 0, stream>>>(x, flat, cnt);

    fused_kernel<<<2048, 256, 0, stream>>>(x,
        WembT, b_emb, WqT, bqkv, WoT, bo, Wf1T, bf1, Wf2C, bf2, WcT, b_comb,
        ln1_s, ln1_b, ln2_s, ln2_b, flat, cnt, out);
}

// Round 6
// 893.207 us; speedup vs baseline: 1.8448x; 1.8448x over previous
//
#include <hip/hip_runtime.h>
#include <hip/hip_bf16.h>
#include <math.h>

#define N_PTS 65534
#define GH 180
#define GW 360
#define NCELL (GH*GW)
#define PI_F 3.14159265358979323846f
#define NSEC 92

typedef __bf16 bf16;
typedef bf16 bf16x8 __attribute__((ext_vector_type(8)));
typedef float f32x4 __attribute__((ext_vector_type(4)));

// wave-level LDS fence: drains LDS queue + compiler memory barrier (R5 lesson: load-bearing).
#define LDS_FENCE() asm volatile("s_waitcnt lgkmcnt(0)" ::: "memory")
// raw barrier: NO compiler vmcnt(0) drain (prefetch loads stay in flight across it)
#define RAW_BAR()   asm volatile("s_barrier" ::: "memory")

static __device__ __forceinline__ f32x4 mfma16(bf16x8 a, bf16x8 b, f32x4 c){
    return __builtin_amdgcn_mfma_f32_16x16x32_bf16(a,b,c,0,0,0);
}

// ---------------- repack all weights into the fragment-ordered stream.
// stream = 92 sections x 16KB. section: 16 units x (64 lanes x 16B).
// unit u element (l=16g+c, j): B[row n][k = ks*32+g*8+j] per tables below.
__global__ void repack_kernel(const float* __restrict__ W_emb,
                              const float* __restrict__ Wqkv,
                              const float* __restrict__ Wo,
                              const float* __restrict__ Wf1,
                              const float* __restrict__ Wf2,
                              const float* __restrict__ W_comb,
                              bf16* __restrict__ stream){
    int idx = blockIdx.x*256 + threadIdx.x;
    if (idx >= NSEC*8192) return;
    int sec = idx >> 13;
    int r   = idx & 8191;
    int u   = r >> 9;
    int e   = r & 511;
    int l   = e >> 3, j = e & 7;
    int g   = l >> 4, c = l & 15;
    float v = 0.f;
    if (sec < 8){                                  // embed: sec=ch, u=nt*3+ks (12 used)
        if (u < 12){
            int nt=u/3, ks=u%3;
            int n = sec*64 + nt*16 + c;
            int k = ks*32 + g*8 + j;
            if (k < 75) v = W_emb[(size_t)k*512 + n];
        }
    } else if (sec < 60){                          // layers
        int lay = (sec-8)/26, s = (sec-8)%26;
        if (s < 8){                                // QKV: s=hd, u=s3*4+ks (12 used)
            if (u < 12){
                int s3=u/4, ks=u%4;
                int col = s3*128 + s*16 + c;
                int k = ks*32 + g*8 + j;
                v = Wqkv[(size_t)lay*49152 + (size_t)k*384 + col];
            }
        } else if (s < 10){                        // O: u=(nh&3)*4+ks
            int nh = (s-8)*4 + u/4, ks = u%4;
            int k = ks*32 + g*8 + j;
            v = Wo[(size_t)lay*16384 + (size_t)k*128 + nh*16 + c];
        } else {                                   // FFN: s-10 = ch*2 + (0:F1,1:F2)
            int t = s-10, ch = t>>1;
            if (!(t&1)){                           // F1: u=nt*4+ks
                int nt=u/4, ks=u%4;
                int n = ch*64 + nt*16 + c;
                int k = ks*32 + g*8 + j;
                v = Wf1[(size_t)lay*65536 + (size_t)k*512 + n];
            } else {                               // F2: u=nt2*2+ks
                int nt2=u/2, ks=u%2;
                int kk = ks*32 + g*8 + j;
                v = Wf2[(size_t)lay*65536 + (size_t)(ch*64+kk)*128 + nt2*16 + c];
            }
        }
    } else {                                       // comb: sec-60=chk, u=tk*4+ks
        int chk = sec-60, tk=u/4, ks=u%4;
        int n = chk*16 + c;
        int k = tk*128 + ks*32 + g*8 + j;
        v = W_comb[(size_t)k*512 + n];
    }
    stream[idx] = (bf16)v;
}

// ---------------- per-point grid index + counts
__global__ void count_kernel(const float* __restrict__ x, int* __restrict__ flat,
                             int* __restrict__ cnt){
    int p = blockIdx.x*256 + threadIdx.x;
    if (p >= N_PTS) return;
    float lat = x[p*24+0], lon = x[p*24+1];
    if (lat == -90.0f) lat += 1e-4f;
    int lati = (int)floorf(90.0f - lat);
    int loni = (180 + (int)floorf(lon + 180.0f)) % 360;
    lati = min(max(lati,0),GH-1);
    loni = min(max(loni,0),GW-1);
    int f = lati*GW + loni;
    flat[p] = f;
    atomicAdd(&cnt[f], 1);
}

// double-buffered section advance: fence+raw-barrier (no vmcnt drain), write prefetched
// section from regs (precise vmcnt wait lands here, one section of compute after issue),
// issue next prefetch, fence+barrier, expose buffer.
#define ADV() do{ \
    LDS_FENCE(); RAW_BAR(); \
    { int4* wb4 = (int4*)&wbuf[sec&1][0]; \
      wb4[tid]=p0; wb4[tid+256]=p1; wb4[tid+512]=p2; wb4[tid+768]=p3; } \
    if (sec+1 < NSEC){ const int4* gp = gs4 + (size_t)(sec+1)*1024; \
      p0=gp[tid]; p1=gp[tid+256]; p2=gp[tid+512]; p3=gp[tid+768]; } \
    LDS_FENCE(); RAW_BAR(); \
    cb = &wbuf[sec&1][0]; sec++; \
}while(0)

#define FRAG(u) (*(const bf16x8*)&cb[(u)*512 + l8])

// params in LDS (bf16): offsets
#define P_EMB  0
#define P_QKV  512
#define P_O    1280
#define P_F1   1536
#define P_F2   2560
#define P_L1S  2816
#define P_L1B  3072
#define P_L2S  3328
#define P_L2B  3584
#define P_CMB  3840

// ================= fully fused: features -> embed -> 2 layers -> comb -> scatter
// wave = 8 points = 32 tokens (2 M-tiles). block = 4 waves sharing the weight stream.
__global__ __launch_bounds__(256,2) void fused_kernel(
    const float* __restrict__ x,
    const bf16* __restrict__ stream,
    const float* __restrict__ b_emb, const float* __restrict__ bqkv,
    const float* __restrict__ bo,    const float* __restrict__ bf1,
    const float* __restrict__ bf2,   const float* __restrict__ b_comb,
    const float* __restrict__ ln1s,  const float* __restrict__ ln1b,
    const float* __restrict__ ln2s,  const float* __restrict__ ln2b,
    const int* __restrict__ flat,    const int* __restrict__ cnt,
    float* __restrict__ out)
{
    __shared__ __align__(16) bf16  tile[4][32][136];  // per-wave transpose tile (34,816 B)
    __shared__ __align__(16) bf16  wbuf[2][8192];     // weight stream dbuf (32,768 B)
    __shared__ __align__(16) bf16  prm[4352];         // params (8,704 B)
    __shared__ __align__(16) float tfb[4][128];       // per-wave embed bounce (2,048 B)
    const int tid = threadIdx.x;
    const int wv = tid>>6, l = tid&63;
    const int g = l>>4, c = l&15;
    const int l8 = l*8;
    const int pb = blockIdx.x*32 + wv*8;

    // ---- params -> LDS (bf16; exact for this problem's 0/1 affine params)
    for (int i=tid; i<4352; i+=256){
        float v;
        if      (i<512)  v=b_emb[i];
        else if (i<1280) v=bqkv[i-512];
        else if (i<1536) v=bo[i-1280];
        else if (i<2560) v=bf1[i-1536];
        else if (i<2816) v=bf2[i-2560];
        else if (i<3072) v=ln1s[i-2816];
        else if (i<3328) v=ln1b[i-3072];
        else if (i<3584) v=ln2s[i-3328];
        else if (i<3840) v=ln2b[i-3584];
        else             v=b_comb[i-3840];
        prm[i]=(bf16)v;
    }

    // ---- scatter indices (hoisted: no global loads later that would drain prefetch)
    int flj[4]; float ivj[4];
    #pragma unroll
    for (int j=0;j<4;++j){
        int p = pb + g*4 + j;
        if (g<2 && p<N_PTS){ int f=flat[p]; flj[j]=f; ivj[j]=1.f/fmaxf((float)cnt[f],1.f); }
        else { flj[j]=0; ivj[j]=0.f; }
    }

    // ---- features into tile rows 0..7 (points), rows 8..15 zeroed (M-tile pad)
    {
        const int pl = l>>3, w = l&7;
        const int p = pb + pl;
        const bool valid = (p < N_PTS);
        float lat=0.f, lon=0.f, t=0.f;
        if (valid){ lat=x[p*24+0]; lon=x[p*24+1]; t=x[p*24+2]; }
        if (lat == -90.0f) lat += 1e-4f;
        float pvs[3] = { -lat - floorf(-lat), lon - floorf(lon), t + 1.0f };
        #pragma unroll
        for (int i=0;i<12;++i){
            int f = w*12 + i;
            float val;
            if (f >= 75) val = 0.f;
            else if (f < 24){
                if (f==0)      val = lat*(1.f/90.f);
                else if (f==1) val = lon*(1.f/180.f);
                else if (f==2) val = t*(1.f/12.f);
                else           val = valid ? x[p*24+f] : 0.f;
            } else if (f<27) val = pvs[f-24];
            else if (f<51){ int q=f-27; val = sinf(pvs[q>>3]*(float)(1<<(q&7))*PI_F); }
            else          { int q=f-51; val = cosf(pvs[q>>3]*(float)(1<<(q&7))*PI_F); }
            if (!valid) val = 0.f;
            tile[wv][pl][f]   = (bf16)val;
            tile[wv][8+pl][f] = (bf16)0.f;
        }
    }
    LDS_FENCE();                     // feature writes -> afe reads
    bf16x8 afe[3];
    #pragma unroll
    for (int ks=0;ks<3;++ks) afe[ks] = *(const bf16x8*)&tile[wv][c][ks*32+g*8];

    // ---- stream init: load section 0 into regs (first ADV writes it)
    const int4* gs4 = (const int4*)stream;
    int4 p0,p1,p2,p3;
    p0=gs4[tid]; p1=gs4[tid+256]; p2=gs4[tid+512]; p3=gs4[tid+768];
    int sec = 0;
    bf16* cb = &wbuf[0][0];
    float* tf = &tfb[wv][0];

    f32x4 h[2][8];
    // ---- embed: 8 sections (ch), per (ch,nt) 16-col f32 bounce for C->h relayout
    #pragma unroll
    for (int ch=0; ch<8; ++ch){
        ADV();
        const int tk = ch>>1;
        const int hn = (ch&1)*4;
        #pragma unroll
        for (int nt=0; nt<4; ++nt){
            f32x4 acc = {0.f,0.f,0.f,0.f};
            #pragma unroll
            for (int ks=0;ks<3;++ks)
                acc = mfma16(afe[ks], FRAG(nt*3+ks), acc);
            float bb = (float)prm[P_EMB + ch*64 + nt*16 + c];
            if (g<2){
                #pragma unroll
                for (int j=0;j<4;++j) tf[(g*4+j)*16 + c] = acc[j] + bb;
            }
            LDS_FENCE();             // tf writes -> tf reads (cross-lane)
            h[0][hn+nt][tk] = tf[g*16 + c];
            h[1][hn+nt][tk] = tf[(4+g)*16 + c];
            LDS_FENCE();             // tf reads -> next tf writes (WAR)
        }
    }

    // ---- transformer layers
    for (int lay=0; lay<2; ++lay){
        float ls[8], lb[8];
        // ===== LN1 -> tile (bf16)
        #pragma unroll
        for (int n=0;n<8;++n){ ls[n]=(float)prm[P_L1S+lay*128+n*16+c]; lb[n]=(float)prm[P_L1B+lay*128+n*16+c]; }
        #pragma unroll
        for (int mt=0;mt<2;++mt)
            #pragma unroll
            for (int j=0;j<4;++j){
                float s=0.f,q=0.f;
                #pragma unroll
                for (int n=0;n<8;++n){ float v=h[mt][n][j]; s+=v; q+=v*v; }
                s += __shfl_xor(s,1); s += __shfl_xor(s,2); s += __shfl_xor(s,4); s += __shfl_xor(s,8);
                q += __shfl_xor(q,1); q += __shfl_xor(q,2); q += __shfl_xor(q,4); q += __shfl_xor(q,8);
                float m = s*(1.f/128.f);
                float var = q*(1.f/128.f) - m*m;
                float rs = rsqrtf(var + 1e-5f);
                #pragma unroll
                for (int n=0;n<8;++n)
                    tile[wv][mt*16+g*4+j][n*16+c] = (bf16)((h[mt][n][j]-m)*rs*ls[n]+lb[n]);
            }
        LDS_FENCE();                 // LN1 writes -> af reads
        bf16x8 af[2][4];
        #pragma unroll
        for (int mt=0;mt<2;++mt)
            #pragma unroll
            for (int ks=0;ks<4;++ks)
                af[mt][ks] = *(const bf16x8*)&tile[wv][mt*16+c][ks*32+g*8];
        LDS_FENCE();                 // af reads -> ot writes (WAR)
        // ===== QKV + in-register attention, per head (sections; ot overwrites tile)
        for (int hd=0; hd<8; ++hd){
            ADV();
            f32x4 acc[3][2];
            #pragma unroll
            for (int s3=0;s3<3;++s3){
                bf16x8 bq[4];
                #pragma unroll
                for (int ks=0;ks<4;++ks) bq[ks] = FRAG(s3*4+ks);
                float bias = (float)prm[P_QKV + lay*384 + s3*128 + hd*16 + c];
                #pragma unroll
                for (int mt=0;mt<2;++mt){
                    f32x4 a = {0.f,0.f,0.f,0.f};
                    #pragma unroll
                    for (int ks=0;ks<4;++ks)
                        a = mfma16(af[mt][ks], bq[ks], a);
                    #pragma unroll
                    for (int j=0;j<4;++j) a[j] += bias;
                    acc[s3][mt] = a;
                }
            }
            #pragma unroll
            for (int mt=0;mt<2;++mt){
                #pragma unroll
                for (int j=0;j<4;++j) acc[0][mt][j] *= 0.25f;
                float att[16];
                #pragma unroll
                for (int i=0;i<4;++i)
                    #pragma unroll
                    for (int j=0;j<4;++j){
                        float t = acc[0][mt][i]*acc[1][mt][j];
                        t += __shfl_xor(t,1); t += __shfl_xor(t,2);
                        t += __shfl_xor(t,4); t += __shfl_xor(t,8);
                        att[i*4+j]=t;
                    }
                #pragma unroll
                for (int i=0;i<4;++i){
                    float m = fmaxf(fmaxf(att[i*4],att[i*4+1]),fmaxf(att[i*4+2],att[i*4+3]));
                    float e0=__expf(att[i*4]-m),   e1=__expf(att[i*4+1]-m);
                    float e2=__expf(att[i*4+2]-m), e3=__expf(att[i*4+3]-m);
                    float inv = 1.f/(e0+e1+e2+e3);
                    float o = (e0*acc[2][mt][0]+e1*acc[2][mt][1]+e2*acc[2][mt][2]+e3*acc[2][mt][3])*inv;
                    tile[wv][mt*16+g*4+i][hd*16+c] = (bf16)o;
                }
            }
        }
        LDS_FENCE();                 // ot writes -> oa reads
        // ===== O-proj (2 sections), residual accumulates in h
        bf16x8 oa[2][4];
        #pragma unroll
        for (int mt=0;mt<2;++mt)
            #pragma unroll
            for (int ks=0;ks<4;++ks)
                oa[mt][ks] = *(const bf16x8*)&tile[wv][mt*16+c][ks*32+g*8];
        LDS_FENCE();                 // oa reads -> LN2 writes (WAR)
        for (int s2=0; s2<2; ++s2){
            ADV();
            #pragma unroll
            for (int n4=0;n4<4;++n4){
                int nh = s2*4+n4;
                bf16x8 bo_[4];
                #pragma unroll
                for (int ks=0;ks<4;++ks) bo_[ks] = FRAG(n4*4+ks);
                float bias = (float)prm[P_O + lay*128 + nh*16 + c];
                #pragma unroll
                for (int mt=0;mt<2;++mt){
                    f32x4 a = h[mt][nh];
                    #pragma unroll
                    for (int ks=0;ks<4;++ks)
                        a = mfma16(oa[mt][ks], bo_[ks], a);
                    #pragma unroll
                    for (int j=0;j<4;++j) a[j]+=bias;
                    h[mt][nh]=a;
                }
            }
        }
        // ===== LN2 -> tile
        #pragma unroll
        for (int n=0;n<8;++n){ ls[n]=(float)prm[P_L2S+lay*128+n*16+c]; lb[n]=(float)prm[P_L2B+lay*128+n*16+c]; }
        #pragma unroll
        for (int mt=0;mt<2;++mt)
            #pragma unroll
            for (int j=0;j<4;++j){
                float s=0.f,q=0.f;
                #pragma unroll
                for (int n=0;n<8;++n){ float v=h[mt][n][j]; s+=v; q+=v*v; }
                s += __shfl_xor(s,1); s += __shfl_xor(s,2); s += __shfl_xor(s,4); s += __shfl_xor(s,8);
                q += __shfl_xor(q,1); q += __shfl_xor(q,2); q += __shfl_xor(q,4); q += __shfl_xor(q,8);
                float m = s*(1.f/128.f);
                float var = q*(1.f/128.f) - m*m;
                float rs = rsqrtf(var + 1e-5f);
                #pragma unroll
                for (int n=0;n<8;++n)
                    tile[wv][mt*16+g*4+j][n*16+c] = (bf16)((h[mt][n][j]-m)*rs*ls[n]+lb[n]);
            }
        LDS_FENCE();                 // LN2 writes -> f1a reads
        bf16x8 f1a[2][4];
        #pragma unroll
        for (int mt=0;mt<2;++mt)
            #pragma unroll
            for (int ks=0;ks<4;++ks)
                f1a[mt][ks] = *(const bf16x8*)&tile[wv][mt*16+c][ks*32+g*8];
        LDS_FENCE();                 // f1a reads -> gt writes (WAR)
        // ===== FFN: per ch: F1 section, GELU -> tile, F2 section accumulates into h
        for (int ch=0; ch<8; ++ch){
            ADV();
            #pragma unroll
            for (int nt=0;nt<4;++nt){
                bf16x8 b1[4];
                #pragma unroll
                for (int ks=0;ks<4;++ks) b1[ks] = FRAG(nt*4+ks);
                float bias = (float)prm[P_F1 + lay*512 + ch*64 + nt*16 + c];
                #pragma unroll
                for (int mt=0;mt<2;++mt){
                    f32x4 a = {0.f,0.f,0.f,0.f};
                    #pragma unroll
                    for (int ks=0;ks<4;++ks)
                        a = mfma16(f1a[mt][ks], b1[ks], a);
                    #pragma unroll
                    for (int j=0;j<4;++j){
                        float xx = a[j]+bias;
                        float zz = 0.7978845608028654f*(xx+0.044715f*xx*xx*xx);
                        float u  = __expf(2.f*zz);
                        float th = (u-1.f)/(u+1.f);
                        tile[wv][mt*16+g*4+j][nt*16+c] = (bf16)(0.5f*xx*(1.f+th));
                    }
                }
            }
            LDS_FENCE();             // gt writes -> ga reads
            bf16x8 ga[2][2];
            #pragma unroll
            for (int mt=0;mt<2;++mt)
                #pragma unroll
                for (int ks=0;ks<2;++ks)
                    ga[mt][ks] = *(const bf16x8*)&tile[wv][mt*16+c][ks*32+g*8];
            LDS_FENCE();             // ga reads -> next gt writes (WAR)
            ADV();
            #pragma unroll
            for (int nt2=0;nt2<8;++nt2){
                bf16x8 b2[2];
                #pragma unroll
                for (int ks=0;ks<2;++ks) b2[ks] = FRAG(nt2*2+ks);
                #pragma unroll
                for (int mt=0;mt<2;++mt){
                    f32x4 a = h[mt][nt2];
                    #pragma unroll
                    for (int ks=0;ks<2;++ks)
                        a = mfma16(ga[mt][ks], b2[ks], a);
                    h[mt][nt2]=a;
                }
            }
        }
        #pragma unroll
        for (int nt2=0;nt2<8;++nt2){
            float bias = (float)prm[P_F2 + lay*128 + nt2*16+c];
            #pragma unroll
            for (int mt=0;mt<2;++mt)
                #pragma unroll
                for (int j=0;j<4;++j) h[mt][nt2][j]+=bias;
        }
    }

    // ---- comb + scatter-mean. tk-split GEMMs reuse the token-major tile.
    #pragma unroll
    for (int mt=0;mt<2;++mt)
        #pragma unroll
        for (int n=0;n<8;++n)
            #pragma unroll
            for (int j=0;j<4;++j)
                tile[wv][mt*16+g*4+j][n*16+c] = (bf16)h[mt][n][j];
    LDS_FENCE();                     // h writes -> afc reads
    bf16x8 afc[4][4];
    #pragma unroll
    for (int tk=0;tk<4;++tk)
        #pragma unroll
        for (int ks=0;ks<4;++ks)
            afc[tk][ks] = *(const bf16x8*)&tile[wv][(c&7)*4+tk][ks*32+g*8];
    for (int chk=0; chk<32; ++chk){
        ADV();
        f32x4 a = {0.f,0.f,0.f,0.f};
        #pragma unroll
        for (int tk=0;tk<4;++tk)
            #pragma unroll
            for (int ks=0;ks<4;++ks)
                a = mfma16(afc[tk][ks], FRAG(tk*4+ks), a);
        if (g<2){
            float bb = (float)prm[P_CMB + chk*16+c];
            #pragma unroll
            for (int j=0;j<4;++j){
                int p = pb + g*4 + j;
                if (p < N_PTS)
                    atomicAdd(&out[(size_t)flj[j]*512 + chk*16 + c], (a[j]+bb)*ivj[j]);
            }
        }
    }
}

extern "C" void kernel_launch(void* const* d_in, const int* in_sizes, int n_in,
                              void* d_out, int out_size, void* d_ws, size_t ws_size,
                              hipStream_t stream){
    (void)in_sizes; (void)n_in; (void)ws_size;
    const float* x      = (const float*)d_in[0];
    const float* W_emb  = (const float*)d_in[1];
    const float* b_emb  = (const float*)d_in[2];
    const float* ln1_s  = (const float*)d_in[3];
    const float* ln1_b  = (const float*)d_in[4];
    const float* Wqkv   = (const float*)d_in[5];
    const float* bqkv   = (const float*)d_in[6];
    const float* Wo     = (const float*)d_in[7];
    const float* bo     = (const float*)d_in[8];
    const float* ln2_s  = (const float*)d_in[9];
    const float* ln2_b  = (const float*)d_in[10];
    const float* Wf1    = (const float*)d_in[11];
    const float* bf1    = (const float*)d_in[12];
    const float* Wf2    = (const float*)d_in[13];
    const float* bf2    = (const float*)d_in[14];
    const float* W_comb = (const float*)d_in[15];
    const float* b_comb = (const float*)d_in[16];
    float* out = (float*)d_out;

    char* ws = (char*)d_ws;
    size_t off = 0;
    auto alloc = [&](size_t bytes)->char*{
        char* p = ws + off; off = (off + bytes + 255) & ~(size_t)255; return p;
    };
    bf16* wstream = (bf16*) alloc((size_t)NSEC*8192*2);
    int*  flat    = (int*)  alloc((size_t)N_PTS*4);
    int*  cnt     = (int*)  alloc((size_t)NCELL*4);

    hipMemsetAsync(d_out, 0, (size_t)out_size*sizeof(float), stream);
    hipMemsetAsync(cnt, 0, (size_t)NCELL*4, stream);

    repack_kernel<<<(NSEC*8192+255)/256, 256, 0, stream>>>(
        W_emb, Wqkv, Wo, Wf1, Wf2, W_comb, wstream);
    count_kernel<<<(N_PTS+255)/256, 256, 0, stream>>>(x, flat, cnt);

    fused_kernel<<<2048, 256, 0, stream>>>(x, wstream,
        b_emb, bqkv, bo, bf1, bf2, b_comb,
        ln1_s, ln1_b, ln2_s, ln2_b, flat, cnt, out);
}